// Round 9
// baseline (125.194 us; speedup 1.0000x reference)
//
#include <hip/hip_runtime.h>
#include <math.h>

// Problem constants
#define BB 16      // batch
#define LL 32      // L
#define AA 2046    // attributor cols
#define MM 2048    // M = A + 2
#define NROWS 192  // 6L

// Workspace layout (floats):
//   uv  [4][16][64]   u0,u1,v0,v1 weights (4096)
//   bnd [2][2][2][16] boundary s/t sums: [j][s|t][user|item][b] (128)
//   c   [2][16][2048] causal weights for target cols {0, M-1} (65536)
//   gg  [16][64][2]   per-value-row reduced sums g_j[b,r] (2048)
//
// Session lessons: R5 — NO device-scope fences (L2 writeback per fence
// serialized 1024 blocks into 76 us). R7 — don't give one thread the full
// 128-row serial loop at 512 waves; R8/R4 — keep >=2048 waves in big kernels.

// ---------------------------------------------------------------------------
// Kernel 0: per-batch prep (16 blocks x 256).
//   K_j[l] = sum_{r=64..127} relu(src_j[b,r]) W2[r,l]   (src_0=user, 1=item)
//   Q_j[l] = sum_{r=0..63}   relu(src_j[b,r]) W2[r,l]
//   u_j[r] = W2[r,:]·K_j  (r<64, weights for s_j)
//   v_j[r] = W2[64+r,:]·Q_j            (weights for t_j)
//   bnd: full boundary-column sums s_j/t_j for n=0 (user) and n=M-1 (item).
// ---------------------------------------------------------------------------
__global__ __launch_bounds__(256) void prep_kernel(
    const float* __restrict__ user, const float* __restrict__ item,
    const float* __restrict__ W2, float* __restrict__ uv,
    float* __restrict__ bnd) {
  const int b = blockIdx.x, t = threadIdx.x;
  __shared__ float KQ[4][LL];   // 0:K0(user) 1:K1(item) 2:Q0(user) 3:Q1(item)
  __shared__ float uvs[4][64];  // 0:u0 1:u1 2:v0 3:v1
  if (t < 128) {
    const int q = t >> 5, l = t & 31;
    const float* __restrict__ src = (q & 1) ? item : user;
    const int rbase = (q < 2) ? 64 : 0;  // K from rows 64..127, Q from 0..63
    float acc = 0.f;
#pragma unroll
    for (int r = 0; r < 64; ++r)
      acc += fmaxf(src[b * NROWS + rbase + r], 0.f) * W2[(rbase + r) * LL + l];
    KQ[q][l] = acc;
  }
  __syncthreads();
  {
    const int which = t >> 6, r = t & 63;
    const int wrow = (which < 2) ? r : 64 + r;
    float acc = 0.f;
#pragma unroll
    for (int l = 0; l < LL; ++l) acc += W2[wrow * LL + l] * KQ[which][l];
    uvs[which][r] = acc;
    uv[which * (BB * 64) + b * 64 + r] = acc;
  }
  __syncthreads();
  if (t < 8) {
    const int which = t & 1, j = (t >> 1) & 1, stv = t >> 2;
    const float* __restrict__ src = which ? item : user;
    float acc = 0.f;
    if (stv == 0) {
#pragma unroll
      for (int r = 0; r < 64; ++r)
        acc += fmaxf(src[b * NROWS + r], 0.f) * uvs[j][r];
    } else {
#pragma unroll
      for (int r = 0; r < 64; ++r)
        acc += fmaxf(src[b * NROWS + 64 + r], 0.f) * uvs[2 + j][r];
    }
    bnd[((j * 2 + stv) * 2 + which) * BB + b] = acc;
  }
}

// ---------------------------------------------------------------------------
// Kernel 1 (stc2): fused s/t + sigmoid -> c, NO part round-trip.
// Block = 64 cols x 4 r-splits (256 thr). Thread (cl, q) sums rows
// [q*32, q*32+32) for its column: q 0,1 -> s-weights u0/u1; q 2,3 -> t v0/v1.
// Lane layout keeps att loads coalesced (consecutive t = consecutive cols).
// 4 KB LDS tile + 1 barrier reduces the r-splits; 64 survivors compute
//   d_j = s_j·adj[n,mj]·iw[n,mj] − t_j·adj[mj,n]·iw[mj,n]
//   c_j = sigmoid(d_j)·adj[n,mj]   (stable exp(min(d,0)) form)
// Boundary cols n=0 / n=M-1 take bnd[] instead (same math as R8's cweight).
// grid (32 coltiles, 16 b) = 512 blocks = 2048 waves.
// ---------------------------------------------------------------------------
__global__ __launch_bounds__(256) void stc2_kernel(
    const float* __restrict__ att, const float* __restrict__ W1,
    const float* __restrict__ uv, const float* __restrict__ adj,
    const float* __restrict__ iw, const float* __restrict__ bnd,
    float* __restrict__ c) {
  const int x = blockIdx.x, b = blockIdx.y, t = threadIdx.x;
  const int cl = t & 63;        // column within tile
  const int q = t >> 6;         // r-split 0..3
  const int col = x * 64 + cl;  // interior column index into att/W1 (0..2045)
  const int n = col + 1;        // node index for interior columns
  const int z = q >> 1;         // 0: s-phase rows, 1: t-phase rows
  const int r0 = q * 32;
  const int wibase = r0 - z * 64;

  const float* __restrict__ w0 = uv + (2 * z) * (BB * 64) + b * 64;
  const float* __restrict__ w1 = uv + (2 * z + 1) * (BB * 64) + b * 64;

  float a0 = 0.f, a1 = 0.f;
  if (col < AA) {
#pragma unroll
    for (int i = 0; i < 32; ++i) {
      const int r = r0 + i;
      const float v = fmaxf(att[(size_t)(b * NROWS + r) * AA + col] *
                                W1[(size_t)r * AA + col],
                            0.f);
      a0 += v * w0[wibase + i];
      a1 += v * w1[wibase + i];
    }
  }
  __shared__ float red[4][2][64];
  red[q][0][cl] = a0;
  red[q][1][cl] = a1;
  __syncthreads();
  if (t >= 64) return;

  // survivors: full s/t for column `col`, then sigmoid -> c
  float s0 = red[0][0][cl] + red[1][0][cl];
  float s1 = red[0][1][cl] + red[1][1][cl];
  float t0v = red[2][0][cl] + red[3][0][cl];
  float t1v = red[2][1][cl] + red[3][1][cl];
  if (col >= AA) return;

  const float an0 = adj[(size_t)n * MM];
  const float an1 = adj[(size_t)n * MM + (MM - 1)];
  const float wn0 = an0 * iw[(size_t)n * MM];
  const float wn1 = an1 * iw[(size_t)n * MM + (MM - 1)];
  const float w0n = adj[n] * iw[n];
  const float w1n =
      adj[(size_t)(MM - 1) * MM + n] * iw[(size_t)(MM - 1) * MM + n];
  const float d0 = s0 * wn0 - t0v * w0n;
  const float d1 = s1 * wn1 - t1v * w1n;
  const float e0 = expf(-fabsf(d0));
  const float e1 = expf(-fabsf(d1));
  const float sig0 = (d0 > 0.f) ? 1.f / (1.f + e0) : e0 / (1.f + e0);
  const float sig1 = (d1 > 0.f) ? 1.f / (1.f + e1) : e1 / (1.f + e1);
  c[b * MM + n] = sig0 * an0;
  c[BB * MM + b * MM + n] = sig1 * an1;
}

// ---------------------------------------------------------------------------
// Kernel 1b (tiny): boundary columns n=0 / n=M-1 of c from bnd[].
// 1 block x 64 thr: (b, which) pairs; same formulas.
// ---------------------------------------------------------------------------
__global__ __launch_bounds__(64) void cbound_kernel(
    const float* __restrict__ adj, const float* __restrict__ iw,
    const float* __restrict__ bnd, float* __restrict__ c) {
  const int t = threadIdx.x;
  const int b = t >> 1, which = t & 1;
  if (b >= BB) return;
  const int n = which ? (MM - 1) : 0;
  const float s0 = bnd[((0 * 2 + 0) * 2 + which) * BB + b];
  const float s1 = bnd[((1 * 2 + 0) * 2 + which) * BB + b];
  const float t0v = bnd[((0 * 2 + 1) * 2 + which) * BB + b];
  const float t1v = bnd[((1 * 2 + 1) * 2 + which) * BB + b];
  const float an0 = adj[(size_t)n * MM];
  const float an1 = adj[(size_t)n * MM + (MM - 1)];
  const float wn0 = an0 * iw[(size_t)n * MM];
  const float wn1 = an1 * iw[(size_t)n * MM + (MM - 1)];
  const float w0n = adj[n] * iw[n];
  const float w1n =
      adj[(size_t)(MM - 1) * MM + n] * iw[(size_t)(MM - 1) * MM + n];
  const float d0 = s0 * wn0 - t0v * w0n;
  const float d1 = s1 * wn1 - t1v * w1n;
  const float e0 = expf(-fabsf(d0));
  const float e1 = expf(-fabsf(d1));
  const float sig0 = (d0 > 0.f) ? 1.f / (1.f + e0) : e0 / (1.f + e0);
  const float sig1 = (d1 > 0.f) ? 1.f / (1.f + e1) : e1 / (1.f + e1);
  c[b * MM + n] = sig0 * an0;
  c[BB * MM + b * MM + n] = sig1 * an1;
}

// ---------------------------------------------------------------------------
// Kernel 2: g_j[b,r] = sum_n relu(raw[b,128+rv,n])·c_j[b,n].
// 256-thr blocks (4096 waves), float2 loads, shuffle + 1-barrier reduce.
// grid (64 rv, 16 b) = 1024 blocks x 256 thr.
// ---------------------------------------------------------------------------
__global__ __launch_bounds__(256) void gather_kernel(
    const float* __restrict__ user, const float* __restrict__ item,
    const float* __restrict__ att, const float* __restrict__ W1,
    const float* __restrict__ c, float* __restrict__ gg) {
  const int rv = blockIdx.x, b = blockIdx.y, t = threadIdx.x;
  const int r = 128 + rv;
  const int gr = b * NROWS + r;
  const float* __restrict__ c0 = c + b * MM;
  const float* __restrict__ c1 = c + BB * MM + b * MM;
  float g0 = 0.f, g1 = 0.f;
#pragma unroll
  for (int i = 0; i < 4; ++i) {
    const int col = i * 512 + 2 * t;
    if (col < AA) {
      const float2 av = ((const float2*)att)[((size_t)gr * AA + col) >> 1];
      const float2 wv = ((const float2*)W1)[((size_t)r * AA + col) >> 1];
      const float v0 = fmaxf(av.x * wv.x, 0.f);
      const float v1 = fmaxf(av.y * wv.y, 0.f);
      g0 += v0 * c0[col + 1] + v1 * c0[col + 2];
      g1 += v0 * c1[col + 1] + v1 * c1[col + 2];
    }
  }
  if (t == 0) {  // boundary cols n=0 (user) / n=M-1 (item)
    const float uval = fmaxf(user[gr], 0.f);
    const float ival = fmaxf(item[gr], 0.f);
    g0 += uval * c0[0] + ival * c0[MM - 1];
    g1 += uval * c1[0] + ival * c1[MM - 1];
  }
#pragma unroll
  for (int o = 32; o > 0; o >>= 1) {
    g0 += __shfl_down(g0, o);
    g1 += __shfl_down(g1, o);
  }
  __shared__ float rg[2][4];
  if ((t & 63) == 0) {
    rg[0][t >> 6] = g0;
    rg[1][t >> 6] = g1;
  }
  __syncthreads();
  if (t == 0) {
    const float s0 = rg[0][0] + rg[0][1] + rg[0][2] + rg[0][3];
    const float s1 = rg[1][0] + rg[1][1] + rg[1][2] + rg[1][3];
    ((float2*)gg)[b * 64 + rv] = make_float2(s0, s1);
  }
}

// ---------------------------------------------------------------------------
// Kernel 3: final projection, writes ALL outputs (no memset needed).
//   out[b,l,j] = sum_rv W2[128+rv,l]·g_j[b,rv]
// grid 16 blocks x 64 thr.
// ---------------------------------------------------------------------------
__global__ __launch_bounds__(64) void proj_kernel(
    const float* __restrict__ W2, const float* __restrict__ gg,
    float* __restrict__ out) {
  const int b = blockIdx.x, t = threadIdx.x;
  const int l = t & 31, j = t >> 5;
  float acc = 0.f;
#pragma unroll
  for (int i = 0; i < 64; ++i)
    acc += W2[(128 + i) * LL + l] * gg[(b * 64 + i) * 2 + j];
  out[b * 64 + l * 2 + j] = acc;
}

extern "C" void kernel_launch(void* const* d_in, const int* in_sizes, int n_in,
                              void* d_out, int out_size, void* d_ws,
                              size_t ws_size, hipStream_t stream) {
  const float* user = (const float*)d_in[0];
  const float* item = (const float*)d_in[1];
  const float* att = (const float*)d_in[2];
  const float* adj = (const float*)d_in[3];
  const float* iw = (const float*)d_in[4];
  const float* W1 = (const float*)d_in[5];
  const float* W2 = (const float*)d_in[6];
  float* out = (float*)d_out;

  float* uv = (float*)d_ws;        // 4*16*64 = 4096 floats
  float* bnd = uv + 4 * BB * 64;   // 128 floats
  float* c = bnd + 128;            // 2*16*2048 = 65536 floats
  float* gg = c + 2 * BB * MM;     // 2048 floats

  prep_kernel<<<dim3(BB), 256, 0, stream>>>(user, item, W2, uv, bnd);
  stc2_kernel<<<dim3(32, BB), 256, 0, stream>>>(att, W1, uv, adj, iw, bnd, c);
  cbound_kernel<<<dim3(1), 64, 0, stream>>>(adj, iw, bnd, c);
  gather_kernel<<<dim3(64, BB), 256, 0, stream>>>(user, item, att, W1, c, gg);
  proj_kernel<<<dim3(BB), 64, 0, stream>>>(W2, gg, out);
}